// Round 1
// baseline (197.899 us; speedup 1.0000x reference)
//
#include <hip/hip_runtime.h>

#define B_  2
#define T_  2048
#define C_  1024
#define H_  16
#define D_  64
#define M_  (B_*T_)   // 4096
#define N1_ (3*C_)    // 3072

typedef short bf16x8 __attribute__((ext_vector_type(8)));
typedef float f32x4 __attribute__((ext_vector_type(4)));
typedef unsigned short u16;
typedef u16 u16x8 __attribute__((ext_vector_type(8)));

__device__ __forceinline__ u16 f2bf(float f) {
  unsigned u = __float_as_uint(f);
  u += 0x7FFFu + ((u >> 16) & 1u);
  return (u16)(u >> 16);
}

__device__ __forceinline__ void gload16(const void* g, void* l) {
  __builtin_amdgcn_global_load_lds((__attribute__((address_space(1))) void*)g,
                                   (__attribute__((address_space(3))) void*)l,
                                   16, 0, 0);
}

// ---------------- fp32 -> bf16 conversion ----------------
__global__ __launch_bounds__(256) void cvt_bf16(const float* __restrict__ in,
                                                u16* __restrict__ out, int n) {
  int i = (blockIdx.x * 256 + threadIdx.x) * 8;
  if (i >= n) return;
  float4 a = *(const float4*)(in + i);
  float4 b = *(const float4*)(in + i + 4);
  u16x8 o;
  o[0] = f2bf(a.x); o[1] = f2bf(a.y); o[2] = f2bf(a.z); o[3] = f2bf(a.w);
  o[4] = f2bf(b.x); o[5] = f2bf(b.y); o[6] = f2bf(b.z); o[7] = f2bf(b.w);
  *(u16x8*)(out + i) = o;
}

// ---------------- shared GEMM mainloop: C += A[M,K] * W[N,K]^T ----------------
// 128x128 tile, BK=32, 4 waves (2x2), each wave 64x64 via 16x16x32 bf16 MFMA.
// LDS linear [128][32]; global source pre-swizzled (granule g ^= (row>>1)&3),
// frag ds_reads apply the same XOR -> 2-way (free) bank aliasing.
__device__ __forceinline__ void gemm_core(const u16* __restrict__ A,
                                          const u16* __restrict__ W,
                                          u16* As, u16* Bs,
                                          f32x4 (&acc)[4][4],
                                          int m0, int n0, int K) {
  int tid = threadIdx.x;
  int lane = tid & 63, wid = tid >> 6;
  int wr = wid >> 1, wc = wid & 1;

  int arow = wid * 16 + (lane >> 2);       // staging row (round 0); +64 for round 1
  int ag = lane & 3;
  int sg = ag ^ ((arow >> 1) & 3);         // pre-swizzled source granule
  const u16* aSrc0 = A + (m0 + arow) * K + sg * 8;
  const u16* aSrc1 = aSrc0 + 64 * K;
  const u16* bSrc0 = W + (n0 + arow) * K + sg * 8;
  const u16* bSrc1 = bSrc0 + 64 * K;
  u16* aDst0 = As + (wid * 16) * 32;
  u16* aDst1 = As + (64 + wid * 16) * 32;
  u16* bDst0 = Bs + (wid * 16) * 32;
  u16* bDst1 = Bs + (64 + wid * 16) * 32;

  int rg = lane >> 4;
  int aoff[4], boff[4];
#pragma unroll
  for (int m = 0; m < 4; ++m) {
    int row = wr * 64 + m * 16 + (lane & 15);
    aoff[m] = row * 32 + (rg ^ ((row >> 1) & 3)) * 8;
    row = wc * 64 + m * 16 + (lane & 15);
    boff[m] = row * 32 + (rg ^ ((row >> 1) & 3)) * 8;
  }

  for (int kt = 0; kt < K / 32; ++kt) {
    int k0 = kt * 32;
    __syncthreads();                        // prior frag reads done
    gload16(aSrc0 + k0, aDst0);
    gload16(aSrc1 + k0, aDst1);
    gload16(bSrc0 + k0, bDst0);
    gload16(bSrc1 + k0, bDst1);
    __syncthreads();                        // compiler drains vmcnt before barrier

    bf16x8 af[4], bfr[4];
#pragma unroll
    for (int m = 0; m < 4; ++m) af[m] = *(const bf16x8*)(As + aoff[m]);
#pragma unroll
    for (int n = 0; n < 4; ++n) bfr[n] = *(const bf16x8*)(Bs + boff[n]);
#pragma unroll
    for (int m = 0; m < 4; ++m)
#pragma unroll
      for (int n = 0; n < 4; ++n)
        acc[m][n] = __builtin_amdgcn_mfma_f32_16x16x32_bf16(af[m], bfr[n], acc[m][n], 0, 0, 0);
  }
}

// ---------------- GEMM1: qkv = x @ W_attn^T + b, scatter to Q/K/Vt ----------------
__global__ __launch_bounds__(256) void gemm_qkv(const u16* __restrict__ A,
                                                const u16* __restrict__ W,
                                                const float* __restrict__ bias,
                                                u16* __restrict__ Qb,
                                                u16* __restrict__ Kb,
                                                u16* __restrict__ Vt) {
  __shared__ __align__(16) u16 As[128 * 32];
  __shared__ __align__(16) u16 Bs[128 * 32];
  f32x4 acc[4][4] = {};
  int m0 = blockIdx.x * 128, n0 = blockIdx.y * 128;
  gemm_core(A, W, As, Bs, acc, m0, n0, C_);

  int lane = threadIdx.x & 63, wid = threadIdx.x >> 6;
  int wr = wid >> 1, wc = wid & 1;
  int rg = lane >> 4, cl = lane & 15;
#pragma unroll
  for (int n = 0; n < 4; ++n) {
    int gn = n0 + wc * 64 + n * 16 + cl;
    float bv = bias[gn];
    int seg = gn >> 10, cc = gn & 1023;
    int h = cc >> 6, d = cc & 63;
#pragma unroll
    for (int m = 0; m < 4; ++m) {
#pragma unroll
      for (int r = 0; r < 4; ++r) {
        int gm = m0 + wr * 64 + m * 16 + rg * 4 + r;
        int b = gm >> 11, t = gm & 2047;
        u16 val = f2bf(acc[m][n][r] + bv);
        int bh = b * 16 + h;
        if (seg == 0)      Qb[(bh * 2048 + t) * 64 + d] = val;
        else if (seg == 1) Kb[(bh * 2048 + t) * 64 + d] = val;
        else               Vt[(bh * 64 + d) * 2048 + t] = val;
      }
    }
  }
}

// ---------------- GEMM2: out = y @ W_proj^T + b (fp32 out) ----------------
__global__ __launch_bounds__(256) void gemm_proj(const u16* __restrict__ A,
                                                 const u16* __restrict__ W,
                                                 const float* __restrict__ bias,
                                                 float* __restrict__ out) {
  __shared__ __align__(16) u16 As[128 * 32];
  __shared__ __align__(16) u16 Bs[128 * 32];
  f32x4 acc[4][4] = {};
  int m0 = blockIdx.x * 128, n0 = blockIdx.y * 128;
  gemm_core(A, W, As, Bs, acc, m0, n0, C_);

  int lane = threadIdx.x & 63, wid = threadIdx.x >> 6;
  int wr = wid >> 1, wc = wid & 1;
  int rg = lane >> 4, cl = lane & 15;
#pragma unroll
  for (int n = 0; n < 4; ++n) {
    int gn = n0 + wc * 64 + n * 16 + cl;
    float bv = bias[gn];
#pragma unroll
    for (int m = 0; m < 4; ++m) {
#pragma unroll
      for (int r = 0; r < 4; ++r) {
        int gm = m0 + wr * 64 + m * 16 + rg * 4 + r;
        out[gm * 1024 + gn] = acc[m][n][r] + bv;
      }
    }
  }
}

// ---------------- flash attention: 1 block = (b,h, 128 q rows), 4 waves ----------------
__global__ __launch_bounds__(256) void attn_fwd(const u16* __restrict__ Qb,
                                                const u16* __restrict__ Kb,
                                                const u16* __restrict__ Vt,
                                                u16* __restrict__ Yb) {
  __shared__ __align__(16) u16 Ks[64 * 64];       // [kv][d], row = 128B, XOR-swizzled
  __shared__ __align__(16) u16 Vs[64 * 64];       // [d][kv], XOR-swizzled
  __shared__ __align__(16) u16 Ps[4 * 32 * 64];   // per-wave P [32][64], XOR-swizzled
  int tid = threadIdx.x, lane = tid & 63, wid = tid >> 6;
  int bh = blockIdx.y;
  int qt = blockIdx.x;
  int qbase = qt * 128;
  const u16* Qp = Qb + bh * (2048 * 64);
  const u16* Kp = Kb + bh * (2048 * 64);
  const u16* Vp = Vt + bh * (64 * 2048);
  int cl = lane & 15, kg = lane >> 4;

  // Q fragments in registers: 32 rows per wave, D=64 -> [fr][kc]
  bf16x8 qf[2][2];
#pragma unroll
  for (int fr = 0; fr < 2; ++fr)
#pragma unroll
    for (int kc = 0; kc < 2; ++kc) {
      int t = qbase + wid * 32 + fr * 16 + cl;
      qf[fr][kc] = *(const bf16x8*)(Qp + t * 64 + kc * 32 + kg * 8);
    }

  f32x4 o[2][4] = {};
  float mrow[2][4], lrow[2][4];
#pragma unroll
  for (int fr = 0; fr < 2; ++fr)
#pragma unroll
    for (int r = 0; r < 4; ++r) { mrow[fr][r] = -1e30f; lrow[fr][r] = 0.f; }

  // staging (pre-swizzled source, linear LDS dest via global_load_lds)
  int srow = wid * 16 + (lane >> 3);
  int sgr = lane & 7;
  int ssw0 = (sgr ^ (srow & 7)) * 8;
  int srow1 = srow + 8;
  int ssw1 = (sgr ^ (srow1 & 7)) * 8;
  u16* KsD0 = Ks + (wid * 16) * 64;
  u16* KsD1 = Ks + (wid * 16 + 8) * 64;
  u16* VsD0 = Vs + (wid * 16) * 64;
  u16* VsD1 = Vs + (wid * 16 + 8) * 64;

  int jmax = (qbase + 127) >> 6;
  for (int j = 0; j <= jmax; ++j) {
    __syncthreads();                      // prior iter's LDS reads done
    gload16(Kp + (j * 64 + srow) * 64 + ssw0, KsD0);
    gload16(Kp + (j * 64 + srow1) * 64 + ssw1, KsD1);
    gload16(Vp + srow * 2048 + j * 64 + ssw0, VsD0);
    gload16(Vp + srow1 * 2048 + j * 64 + ssw1, VsD1);
    __syncthreads();

    // S = Q K^T
    f32x4 s[2][4] = {};
#pragma unroll
    for (int fc = 0; fc < 4; ++fc) {
#pragma unroll
      for (int kc = 0; kc < 2; ++kc) {
        int row = fc * 16 + cl;
        bf16x8 kf = *(const bf16x8*)(Ks + row * 64 + ((kc * 4 + kg) ^ (row & 7)) * 8);
        s[0][fc] = __builtin_amdgcn_mfma_f32_16x16x32_bf16(qf[0][kc], kf, s[0][fc], 0, 0, 0);
        s[1][fc] = __builtin_amdgcn_mfma_f32_16x16x32_bf16(qf[1][kc], kf, s[1][fc], 0, 0, 0);
      }
    }

    // online softmax (rows live in 16-lane groups; shfl_xor reduce)
#pragma unroll
    for (int fr = 0; fr < 2; ++fr) {
      float rmax[4] = {-1e30f, -1e30f, -1e30f, -1e30f};
#pragma unroll
      for (int fc = 0; fc < 4; ++fc) {
        int kk = j * 64 + fc * 16 + cl;
#pragma unroll
        for (int r = 0; r < 4; ++r) {
          int q = qbase + wid * 32 + fr * 16 + kg * 4 + r;
          float v = (kk <= q) ? s[fr][fc][r] * 0.125f : -1e30f;
          s[fr][fc][r] = v;
          rmax[r] = fmaxf(rmax[r], v);
        }
      }
#pragma unroll
      for (int off = 8; off; off >>= 1)
#pragma unroll
        for (int r = 0; r < 4; ++r)
          rmax[r] = fmaxf(rmax[r], __shfl_xor(rmax[r], off));
      float rsum[4];
#pragma unroll
      for (int r = 0; r < 4; ++r) {
        float mnew = fmaxf(mrow[fr][r], rmax[r]);
        float al = __expf(mrow[fr][r] - mnew);
        mrow[fr][r] = mnew;
        lrow[fr][r] *= al;
        rsum[r] = 0.f;
#pragma unroll
        for (int dc = 0; dc < 4; ++dc) o[fr][dc][r] *= al;
      }
#pragma unroll
      for (int fc = 0; fc < 4; ++fc)
#pragma unroll
        for (int r = 0; r < 4; ++r) {
          float p = __expf(s[fr][fc][r] - mrow[fr][r]);
          s[fr][fc][r] = p;
          rsum[r] += p;
        }
#pragma unroll
      for (int off = 8; off; off >>= 1)
#pragma unroll
        for (int r = 0; r < 4; ++r)
          rsum[r] += __shfl_xor(rsum[r], off);
#pragma unroll
      for (int r = 0; r < 4; ++r) lrow[fr][r] += rsum[r];
      // write P (C-layout -> A-layout via per-wave LDS tile)
#pragma unroll
      for (int fc = 0; fc < 4; ++fc)
#pragma unroll
        for (int r = 0; r < 4; ++r) {
          int prow = fr * 16 + kg * 4 + r;
          int pcol = fc * 16 + cl;
          Ps[wid * 2048 + prow * 64 + (((pcol >> 3) ^ (prow & 7)) * 8) + (pcol & 7)] =
              f2bf(s[fr][fc][r]);
        }
    }
    __syncthreads();                       // P visible (and keeps waves in lockstep)

    // O += P V
#pragma unroll
    for (int kc = 0; kc < 2; ++kc) {
      int prow0 = cl;
      bf16x8 pf0 = *(const bf16x8*)(Ps + wid * 2048 + prow0 * 64 + ((kc * 4 + kg) ^ (prow0 & 7)) * 8);
      int prow1 = 16 + cl;
      bf16x8 pf1 = *(const bf16x8*)(Ps + wid * 2048 + prow1 * 64 + ((kc * 4 + kg) ^ (prow1 & 7)) * 8);
#pragma unroll
      for (int dc = 0; dc < 4; ++dc) {
        int vrow = dc * 16 + cl;
        bf16x8 vf = *(const bf16x8*)(Vs + vrow * 64 + ((kc * 4 + kg) ^ (vrow & 7)) * 8);
        o[0][dc] = __builtin_amdgcn_mfma_f32_16x16x32_bf16(pf0, vf, o[0][dc], 0, 0, 0);
        o[1][dc] = __builtin_amdgcn_mfma_f32_16x16x32_bf16(pf1, vf, o[1][dc], 0, 0, 0);
      }
    }
  }

  // epilogue: y[b,t,h,d] = O / l
  int b = bh >> 4, h = bh & 15;
#pragma unroll
  for (int fr = 0; fr < 2; ++fr)
#pragma unroll
    for (int dc = 0; dc < 4; ++dc)
#pragma unroll
      for (int r = 0; r < 4; ++r) {
        int t = qbase + wid * 32 + fr * 16 + kg * 4 + r;
        int d = dc * 16 + cl;
        Yb[(b * 2048 + t) * 1024 + h * 64 + d] = f2bf(o[fr][dc][r] / lrow[fr][r]);
      }
}

extern "C" void kernel_launch(void* const* d_in, const int* in_sizes, int n_in,
                              void* d_out, int out_size, void* d_ws, size_t ws_size,
                              hipStream_t stream) {
  const float* x  = (const float*)d_in[0];
  const float* Wa = (const float*)d_in[1];
  const float* ba = (const float*)d_in[2];
  const float* Wp = (const float*)d_in[3];
  const float* bp = (const float*)d_in[4];
  float* out = (float*)d_out;

  u16* xb  = (u16*)d_ws;                       //  8 MB  [M,C] bf16
  u16* Wab = xb  + (size_t)M_ * C_;            //  6 MB  [3C,C]
  u16* Wpb = Wab + (size_t)N1_ * C_;           //  2 MB  [C,C]
  u16* Qb  = Wpb + (size_t)C_ * C_;            //  8 MB  [B,H,T,D]
  u16* Kb  = Qb  + (size_t)M_ * C_;            //  8 MB  [B,H,T,D]
  u16* Vt  = Kb  + (size_t)M_ * C_;            //  8 MB  [B,H,D,T]
  u16* Yb  = Vt  + (size_t)M_ * C_;            //  8 MB  [B,T,H*D]

  cvt_bf16<<<(M_ * C_) / 2048, 256, 0, stream>>>(x, xb, M_ * C_);
  cvt_bf16<<<(N1_ * C_) / 2048, 256, 0, stream>>>(Wa, Wab, N1_ * C_);
  cvt_bf16<<<(C_ * C_) / 2048, 256, 0, stream>>>(Wp, Wpb, C_ * C_);
  gemm_qkv<<<dim3(M_ / 128, N1_ / 128), 256, 0, stream>>>(xb, Wab, ba, Qb, Kb, Vt);
  attn_fwd<<<dim3(T_ / 128, B_ * H_), 256, 0, stream>>>(Qb, Kb, Vt, Yb);
  gemm_proj<<<dim3(M_ / 128, C_ / 128), 256, 0, stream>>>(Yb, Wpb, bp, out);
}

// Round 2
// 161.107 us; speedup vs baseline: 1.2284x; 1.2284x over previous
//
#include <hip/hip_runtime.h>

#define B_  2
#define T_  2048
#define C_  1024
#define H_  16
#define D_  64
#define M_  (B_*T_)   // 4096
#define N1_ (3*C_)    // 3072

typedef short bf16x8 __attribute__((ext_vector_type(8)));
typedef float f32x4 __attribute__((ext_vector_type(4)));
typedef unsigned short u16;
typedef u16 u16x8 __attribute__((ext_vector_type(8)));

__device__ __forceinline__ u16 f2bf(float f) {
  unsigned u = __float_as_uint(f);
  u += 0x7FFFu + ((u >> 16) & 1u);
  return (u16)(u >> 16);
}

__device__ __forceinline__ void gload16(const void* g, void* l) {
  __builtin_amdgcn_global_load_lds((__attribute__((address_space(1))) void*)g,
                                   (__attribute__((address_space(3))) void*)l,
                                   16, 0, 0);
}

// ---------------- fp32 -> bf16 conversion ----------------
__global__ __launch_bounds__(256) void cvt_bf16(const float* __restrict__ in,
                                                u16* __restrict__ out, int n) {
  int i = (blockIdx.x * 256 + threadIdx.x) * 8;
  if (i >= n) return;
  float4 a = *(const float4*)(in + i);
  float4 b = *(const float4*)(in + i + 4);
  u16x8 o;
  o[0] = f2bf(a.x); o[1] = f2bf(a.y); o[2] = f2bf(a.z); o[3] = f2bf(a.w);
  o[4] = f2bf(b.x); o[5] = f2bf(b.y); o[6] = f2bf(b.z); o[7] = f2bf(b.w);
  *(u16x8*)(out + i) = o;
}

// ---------------- shared GEMM mainloop: C += A[M,K] * W[N,K]^T ----------------
__device__ __forceinline__ void gemm_core(const u16* __restrict__ A,
                                          const u16* __restrict__ W,
                                          u16* As, u16* Bs,
                                          f32x4 (&acc)[4][4],
                                          int m0, int n0, int K) {
  int tid = threadIdx.x;
  int lane = tid & 63, wid = tid >> 6;
  int wr = wid >> 1, wc = wid & 1;

  int arow = wid * 16 + (lane >> 2);
  int ag = lane & 3;
  int sg = ag ^ ((arow >> 1) & 3);
  const u16* aSrc0 = A + (m0 + arow) * K + sg * 8;
  const u16* aSrc1 = aSrc0 + 64 * K;
  const u16* bSrc0 = W + (n0 + arow) * K + sg * 8;
  const u16* bSrc1 = bSrc0 + 64 * K;
  u16* aDst0 = As + (wid * 16) * 32;
  u16* aDst1 = As + (64 + wid * 16) * 32;
  u16* bDst0 = Bs + (wid * 16) * 32;
  u16* bDst1 = Bs + (64 + wid * 16) * 32;

  int rg = lane >> 4;
  int aoff[4], boff[4];
#pragma unroll
  for (int m = 0; m < 4; ++m) {
    int row = wr * 64 + m * 16 + (lane & 15);
    aoff[m] = row * 32 + (rg ^ ((row >> 1) & 3)) * 8;
    row = wc * 64 + m * 16 + (lane & 15);
    boff[m] = row * 32 + (rg ^ ((row >> 1) & 3)) * 8;
  }

  for (int kt = 0; kt < K / 32; ++kt) {
    int k0 = kt * 32;
    __syncthreads();
    gload16(aSrc0 + k0, aDst0);
    gload16(aSrc1 + k0, aDst1);
    gload16(bSrc0 + k0, bDst0);
    gload16(bSrc1 + k0, bDst1);
    __syncthreads();

    bf16x8 af[4], bfr[4];
#pragma unroll
    for (int m = 0; m < 4; ++m) af[m] = *(const bf16x8*)(As + aoff[m]);
#pragma unroll
    for (int n = 0; n < 4; ++n) bfr[n] = *(const bf16x8*)(Bs + boff[n]);
#pragma unroll
    for (int m = 0; m < 4; ++m)
#pragma unroll
      for (int n = 0; n < 4; ++n)
        acc[m][n] = __builtin_amdgcn_mfma_f32_16x16x32_bf16(af[m], bfr[n], acc[m][n], 0, 0, 0);
  }
}

// ---------------- GEMM1: qkv = x @ W_attn^T + b; Q pre-scaled by 1/8 ----------------
__global__ __launch_bounds__(256) void gemm_qkv(const u16* __restrict__ A,
                                                const u16* __restrict__ W,
                                                const float* __restrict__ bias,
                                                u16* __restrict__ Qb,
                                                u16* __restrict__ Kb,
                                                u16* __restrict__ Vt) {
  __shared__ __align__(16) u16 As[128 * 32];
  __shared__ __align__(16) u16 Bs[128 * 32];
  f32x4 acc[4][4] = {};
  int m0 = blockIdx.x * 128, n0 = blockIdx.y * 128;
  gemm_core(A, W, As, Bs, acc, m0, n0, C_);

  int lane = threadIdx.x & 63, wid = threadIdx.x >> 6;
  int wr = wid >> 1, wc = wid & 1;
  int rg = lane >> 4, cl = lane & 15;
#pragma unroll
  for (int n = 0; n < 4; ++n) {
    int gn = n0 + wc * 64 + n * 16 + cl;
    float bv = bias[gn];
    int seg = gn >> 10, cc = gn & 1023;
    int h = cc >> 6, d = cc & 63;
    float sc = (seg == 0) ? 0.125f : 1.0f;   // fold 1/sqrt(D) into Q
#pragma unroll
    for (int m = 0; m < 4; ++m) {
#pragma unroll
      for (int r = 0; r < 4; ++r) {
        int gm = m0 + wr * 64 + m * 16 + rg * 4 + r;
        int b = gm >> 11, t = gm & 2047;
        u16 val = f2bf((acc[m][n][r] + bv) * sc);
        int bh = b * 16 + h;
        if (seg == 0)      Qb[(bh * 2048 + t) * 64 + d] = val;
        else if (seg == 1) Kb[(bh * 2048 + t) * 64 + d] = val;
        else               Vt[(bh * 64 + d) * 2048 + t] = val;
      }
    }
  }
}

// ---------------- GEMM2: out = y @ W_proj^T + b (fp32 out) ----------------
__global__ __launch_bounds__(256) void gemm_proj(const u16* __restrict__ A,
                                                 const u16* __restrict__ W,
                                                 const float* __restrict__ bias,
                                                 float* __restrict__ out) {
  __shared__ __align__(16) u16 As[128 * 32];
  __shared__ __align__(16) u16 Bs[128 * 32];
  f32x4 acc[4][4] = {};
  int m0 = blockIdx.x * 128, n0 = blockIdx.y * 128;
  gemm_core(A, W, As, Bs, acc, m0, n0, C_);

  int lane = threadIdx.x & 63, wid = threadIdx.x >> 6;
  int wr = wid >> 1, wc = wid & 1;
  int rg = lane >> 4, cl = lane & 15;
#pragma unroll
  for (int n = 0; n < 4; ++n) {
    int gn = n0 + wc * 64 + n * 16 + cl;
    float bv = bias[gn];
#pragma unroll
    for (int m = 0; m < 4; ++m) {
#pragma unroll
      for (int r = 0; r < 4; ++r) {
        int gm = m0 + wr * 64 + m * 16 + rg * 4 + r;
        out[gm * 1024 + gn] = acc[m][n][r] + bv;
      }
    }
  }
}

// ---------------- flash attention v2: QBLK=64, 4 waves x 16 rows ----------------
// grid = 1024 1D blocks; id remapped so each CU's 4 resident blocks pair
// qt with 31-qt (constant causal work per CU). Double-buffered K/V, one
// barrier per KV step, per-wave P tile (no barrier), diag-only masking,
// defer-max rescale.
__global__ __launch_bounds__(256) void attn_fwd(const u16* __restrict__ Qb,
                                                const u16* __restrict__ Kb,
                                                const u16* __restrict__ Vt,
                                                u16* __restrict__ Yb) {
  __shared__ __align__(16) u16 Ks[2][64 * 64];
  __shared__ __align__(16) u16 Vs[2][64 * 64];
  __shared__ __align__(16) u16 Ps[4][16 * 64];
  int tid = threadIdx.x, lane = tid & 63, wid = tid >> 6;
  int id = blockIdx.x;
  int hi = id >> 8, lo = id & 255;
  int bh = (lo >> 5) | (hi << 3);
  int q0l = lo & 31;
  int qt = (hi & 1) ? (31 - q0l) : q0l;
  int qbase = qt * 64;
  const u16* Qp = Qb + bh * (2048 * 64);
  const u16* Kp = Kb + bh * (2048 * 64);
  const u16* Vp = Vt + bh * (64 * 2048);
  int cl = lane & 15, kg = lane >> 4;

  // Q fragments (16 rows/wave, D=64): pre-scaled by 1/8 in gemm_qkv
  bf16x8 qf[2];
#pragma unroll
  for (int kc = 0; kc < 2; ++kc)
    qf[kc] = *(const bf16x8*)(Qp + (qbase + wid * 16 + cl) * 64 + kc * 32 + kg * 8);

  f32x4 o[4] = {};
  float mrow[4], lrow[4];
#pragma unroll
  for (int r = 0; r < 4; ++r) { mrow[r] = -1e30f; lrow[r] = 0.f; }

  // staging geometry: per wave, 8 rows x 64 elems per round, 2 rounds
  int srow = wid * 8 + (lane >> 3);
  int sg8 = ((lane & 7) ^ (lane >> 3)) * 8;   // pre-swizzled source granule

#define STAGE(J, BUF) do {                                        \
    const u16* ksrc = Kp + ((J) * 64 + srow) * 64 + sg8;          \
    const u16* vsrc = Vp + srow * 2048 + (J) * 64 + sg8;          \
    u16* kd = &Ks[BUF][(wid * 8) * 64];                           \
    u16* vd = &Vs[BUF][(wid * 8) * 64];                           \
    gload16(ksrc, kd);                                            \
    gload16(ksrc + 32 * 64, kd + 32 * 64);                        \
    gload16(vsrc, vd);                                            \
    gload16(vsrc + 32 * 2048, vd + 32 * 64);                      \
  } while (0)

  STAGE(0, 0);
  __syncthreads();

  for (int j = 0; j <= qt; ++j) {
    int cur = j & 1;
    if (j < qt) STAGE(j + 1, cur ^ 1);     // prefetch overlaps compute below
    const u16* KsC = Ks[cur];
    const u16* VsC = Vs[cur];
    bool diag = (j == qt);
    int fcTop = diag ? wid : 3;

    // S = Q K^T  (skip fully-masked sub-tiles on the diagonal step)
    f32x4 s[4];
#pragma unroll
    for (int fc = 0; fc < 4; ++fc) {
      if (fc <= fcTop) {
        f32x4 acc = {};
#pragma unroll
        for (int kc = 0; kc < 2; ++kc) {
          int row = fc * 16 + cl;
          bf16x8 kf = *(const bf16x8*)(KsC + row * 64 + (((kc * 4 + kg) ^ (row & 7)) * 8));
          acc = __builtin_amdgcn_mfma_f32_16x16x32_bf16(qf[kc], kf, acc, 0, 0, 0);
        }
        s[fc] = acc;
      } else {
        s[fc][0] = -1e30f; s[fc][1] = -1e30f; s[fc][2] = -1e30f; s[fc][3] = -1e30f;
      }
    }
    if (diag) {
      int qloc = wid * 16 + kg * 4;
#pragma unroll
      for (int fc = 0; fc < 4; ++fc)
#pragma unroll
        for (int r = 0; r < 4; ++r)
          if (fc * 16 + cl > qloc + r) s[fc][r] = -1e30f;
    }

    // online softmax (row = kg*4+r; reduce over 16 lanes of cl)
    float rmax[4] = {-1e30f, -1e30f, -1e30f, -1e30f};
#pragma unroll
    for (int fc = 0; fc < 4; ++fc)
#pragma unroll
      for (int r = 0; r < 4; ++r) rmax[r] = fmaxf(rmax[r], s[fc][r]);
#pragma unroll
    for (int off = 8; off; off >>= 1)
#pragma unroll
      for (int r = 0; r < 4; ++r) rmax[r] = fmaxf(rmax[r], __shfl_xor(rmax[r], off));

    bool ok = (rmax[0] <= mrow[0] + 8.f) && (rmax[1] <= mrow[1] + 8.f) &&
              (rmax[2] <= mrow[2] + 8.f) && (rmax[3] <= mrow[3] + 8.f);
    if (!__all(ok)) {
#pragma unroll
      for (int r = 0; r < 4; ++r) {
        float mnew = fmaxf(mrow[r], rmax[r]);
        float al = __expf(mrow[r] - mnew);
        mrow[r] = mnew;
        lrow[r] *= al;
#pragma unroll
        for (int dc = 0; dc < 4; ++dc) o[dc][r] *= al;
      }
    }
    float rsum[4] = {0.f, 0.f, 0.f, 0.f};
#pragma unroll
    for (int fc = 0; fc < 4; ++fc)
#pragma unroll
      for (int r = 0; r < 4; ++r) {
        float p = __expf(s[fc][r] - mrow[r]);
        s[fc][r] = p;
        rsum[r] += p;
      }
#pragma unroll
    for (int off = 8; off; off >>= 1)
#pragma unroll
      for (int r = 0; r < 4; ++r) rsum[r] += __shfl_xor(rsum[r], off);
#pragma unroll
    for (int r = 0; r < 4; ++r) lrow[r] += rsum[r];

    // write P (per-wave tile, swizzled; same-wave LDS ordering, no barrier)
    u16* Pw = Ps[wid];
#pragma unroll
    for (int fc = 0; fc < 4; ++fc)
#pragma unroll
      for (int r = 0; r < 4; ++r) {
        int prow = kg * 4 + r, pcol = fc * 16 + cl;
        Pw[prow * 64 + (((pcol >> 3) ^ (prow & 7)) * 8) + (pcol & 7)] = f2bf(s[fc][r]);
      }

    // O += P V
#pragma unroll
    for (int kc = 0; kc < 2; ++kc) {
      bf16x8 pf = *(const bf16x8*)(Pw + cl * 64 + (((kc * 4 + kg) ^ (cl & 7)) * 8));
#pragma unroll
      for (int dc = 0; dc < 4; ++dc) {
        int vrow = dc * 16 + cl;
        bf16x8 vf = *(const bf16x8*)(VsC + vrow * 64 + (((kc * 4 + kg) ^ (vrow & 7)) * 8));
        o[dc] = __builtin_amdgcn_mfma_f32_16x16x32_bf16(pf, vf, o[dc], 0, 0, 0);
      }
    }
    __syncthreads();   // prefetch drained + all waves done with cur buffer
  }
#undef STAGE

  // epilogue: y[b,t,h,d] = O / l
  int b = bh >> 4, h = bh & 15;
  float inv[4];
#pragma unroll
  for (int r = 0; r < 4; ++r) inv[r] = 1.f / lrow[r];
#pragma unroll
  for (int dc = 0; dc < 4; ++dc)
#pragma unroll
    for (int r = 0; r < 4; ++r) {
      int t = qbase + wid * 16 + kg * 4 + r;
      int d = dc * 16 + cl;
      Yb[(b * 2048 + t) * 1024 + h * 64 + d] = f2bf(o[dc][r] * inv[r]);
    }
}

extern "C" void kernel_launch(void* const* d_in, const int* in_sizes, int n_in,
                              void* d_out, int out_size, void* d_ws, size_t ws_size,
                              hipStream_t stream) {
  const float* x  = (const float*)d_in[0];
  const float* Wa = (const float*)d_in[1];
  const float* ba = (const float*)d_in[2];
  const float* Wp = (const float*)d_in[3];
  const float* bp = (const float*)d_in[4];
  float* out = (float*)d_out;

  u16* xb  = (u16*)d_ws;
  u16* Wab = xb  + (size_t)M_ * C_;
  u16* Wpb = Wab + (size_t)N1_ * C_;
  u16* Qb  = Wpb + (size_t)C_ * C_;
  u16* Kb  = Qb  + (size_t)M_ * C_;
  u16* Vt  = Kb  + (size_t)M_ * C_;
  u16* Yb  = Vt  + (size_t)M_ * C_;

  cvt_bf16<<<(M_ * C_) / 2048, 256, 0, stream>>>(x, xb, M_ * C_);
  cvt_bf16<<<(N1_ * C_) / 2048, 256, 0, stream>>>(Wa, Wab, N1_ * C_);
  cvt_bf16<<<(C_ * C_) / 2048, 256, 0, stream>>>(Wp, Wpb, C_ * C_);
  gemm_qkv<<<dim3(M_ / 128, N1_ / 128), 256, 0, stream>>>(xb, Wab, ba, Qb, Kb, Vt);
  attn_fwd<<<1024, 256, 0, stream>>>(Qb, Kb, Vt, Yb);
  gemm_proj<<<dim3(M_ / 128, C_ / 128), 256, 0, stream>>>(Yb, Wpb, bp, out);
}